// Round 1
// baseline (2285.588 us; speedup 1.0000x reference)
//
#include <hip/hip_runtime.h>

#define TT 128
#define DD 256
#define HH 8
#define DK 32
#define SCALEF 0.17677669529663687f
#define NEGV -1e9f

// ---------------------------------------------------------------------------
// Kernel 1: per (b,n,h) block. Computes conv-Q slice, conv-K slice, V-proj
// slice (all fp32, staged through LDS scratch), then flash-style attention.
// Writes x (pre-output-projection) into xout (= d_out used as scratch).
// ---------------------------------------------------------------------------
__global__ __launch_bounds__(256, 2) void fused_attn_kernel(
    const float* __restrict__ query,
    const float* __restrict__ key,
    const float* __restrict__ value,
    const unsigned char* __restrict__ kpm8,
    const int* __restrict__ kpm32,
    const int* __restrict__ amask,
    const float* __restrict__ wq, const float* __restrict__ bq,
    const float* __restrict__ wk, const float* __restrict__ bk,
    const float* __restrict__ vw, const float* __restrict__ vb,
    float* __restrict__ xout)
{
    __shared__ float qh[TT * DK];   // 16 KB
    __shared__ float kh[TT * DK];   // 16 KB
    __shared__ float vh[TT * DK];   // 16 KB
    __shared__ float scr[4096];     // 16 KB scratch (staging / masks / merge)

    const int tid = threadIdx.x;
    const int bn = blockIdx.x >> 3;
    const int h  = blockIdx.x & 7;
    const int tx = tid & 15;   // output col pair: j = tx*2 + {0,1}
    const int ty = tid >> 4;   // output rows: t = ty + r*16, r = 0..7

    // ---- detect key_padding_mask storage width (uint8 vs int32) ----
    // If stored as int32, every byte at (i % 4 != 0) is zero. If uint8 of
    // random 0/1, many of those bytes are nonzero.
    bool loc = false;
    for (int i = tid; i < 4096; i += 256) {
        if ((i & 3) && kpm8[i]) loc = true;
    }
    if (tid == 0) scr[0] = 0.f;
    __syncthreads();
    if (loc) scr[0] = 1.f;
    __syncthreads();
    const bool kpm_is_u8 = (scr[0] != 0.f);
    // conv loop's top __syncthreads() protects scr before overwrite

    // ================= conv projections: which=0 -> Q, which=1 -> K ========
    const float* Xc[2];
    Xc[0] = query + (size_t)bn * TT * DD;
    Xc[1] = key   + (size_t)bn * TT * DD;
    const float* Wc[2]; Wc[0] = wq; Wc[1] = wk;
    const float* Bc[2]; Bc[0] = bq; Bc[1] = bk;

    for (int which = 0; which < 2; ++which) {
        const float* __restrict__ X = Xc[which];
        const float* __restrict__ W = Wc[which];
        float acc0[8], acc1[8];
        {
            float b0 = Bc[which][h * DK + tx * 2];
            float b1 = Bc[which][h * DK + tx * 2 + 1];
            #pragma unroll
            for (int r = 0; r < 8; ++r) { acc0[r] = b0; acc1[r] = b1; }
        }
        for (int cc = 0; cc < 16; ++cc) {      // 16 ci-chunks of 16
            __syncthreads();
            float* Xs = scr;           // [130][16]  rows -1..128 (zero-padded)
            float* Ws = scr + 2080;    // [(ci*3 + k)*32 + j], 1536 floats
            for (int i = tid; i < 130 * 16; i += 256) {
                int row = i >> 4, ci = i & 15;
                int g = row - 1;
                Xs[i] = (g >= 0 && g < TT) ? X[g * DD + cc * 16 + ci] : 0.f;
            }
            for (int i = tid; i < 1536; i += 256) {
                int j = i / 48, rem = i % 48;
                int ci = rem / 3, k = rem - ci * 3;
                Ws[(ci * 3 + k) * 32 + j] =
                    W[(h * DK + j) * 768 + (cc * 16 + ci) * 3 + k];
            }
            __syncthreads();
            #pragma unroll
            for (int k = 0; k < 3; ++k) {
                #pragma unroll
                for (int ci4 = 0; ci4 < 4; ++ci4) {
                    float2 w[4];
                    #pragma unroll
                    for (int c = 0; c < 4; ++c)
                        w[c] = *(const float2*)&Ws[((ci4 * 4 + c) * 3 + k) * 32 + tx * 2];
                    #pragma unroll
                    for (int r = 0; r < 8; ++r) {
                        float4 x4 = *(const float4*)&Xs[(ty + r * 16 + k) * 16 + ci4 * 4];
                        acc0[r] += x4.x * w[0].x + x4.y * w[1].x + x4.z * w[2].x + x4.w * w[3].x;
                        acc1[r] += x4.x * w[0].y + x4.y * w[1].y + x4.z * w[2].y + x4.w * w[3].y;
                    }
                }
            }
        }
        __syncthreads();
        float* dst = which ? kh : qh;
        #pragma unroll
        for (int r = 0; r < 8; ++r) {
            int t = ty + r * 16;
            dst[t * DK + tx * 2]     = acc0[r];
            dst[t * DK + tx * 2 + 1] = acc1[r];
        }
    }

    // ================= V projection (K=256 GEMM slice) =====================
    {
        const float* __restrict__ Xv = value + (size_t)bn * TT * DD;
        float acc0[8], acc1[8];
        {
            float b0 = vb[h * DK + tx * 2];
            float b1 = vb[h * DK + tx * 2 + 1];
            #pragma unroll
            for (int r = 0; r < 8; ++r) { acc0[r] = b0; acc1[r] = b1; }
        }
        for (int cc = 0; cc < 16; ++cc) {
            __syncthreads();
            float* Xs = scr;           // [128][16]
            float* Ws = scr + 2048;    // [ci*32 + j], 512 floats
            for (int i = tid; i < 128 * 16; i += 256) {
                int row = i >> 4, ci = i & 15;
                Xs[i] = Xv[row * DD + cc * 16 + ci];
            }
            for (int i = tid; i < 512; i += 256) {
                int j = i >> 4, ci = i & 15;
                Ws[ci * 32 + j] = vw[(h * DK + j) * DD + cc * 16 + ci];
            }
            __syncthreads();
            #pragma unroll
            for (int ci4 = 0; ci4 < 4; ++ci4) {
                float2 w[4];
                #pragma unroll
                for (int c = 0; c < 4; ++c)
                    w[c] = *(const float2*)&Ws[(ci4 * 4 + c) * 32 + tx * 2];
                #pragma unroll
                for (int r = 0; r < 8; ++r) {
                    float4 x4 = *(const float4*)&Xs[(ty + r * 16) * 16 + ci4 * 4];
                    acc0[r] += x4.x * w[0].x + x4.y * w[1].x + x4.z * w[2].x + x4.w * w[3].x;
                    acc1[r] += x4.x * w[0].y + x4.y * w[1].y + x4.z * w[2].y + x4.w * w[3].y;
                }
            }
        }
        __syncthreads();
        #pragma unroll
        for (int r = 0; r < 8; ++r) {
            int t = ty + r * 16;
            vh[t * DK + tx * 2]     = acc0[r];
            vh[t * DK + tx * 2 + 1] = acc1[r];
        }
    }

    // ================= flash attention: 2 threads per q-row ================
    __syncthreads();
    if (tid < TT) {
        int mv = kpm_is_u8 ? (int)kpm8[bn * TT + tid] : kpm32[bn * TT + tid];
        scr[tid] = mv ? 1.f : 0.f;   // 1 = masked out
    }
    __syncthreads();

    const int tq = tid >> 1;
    const int half = tid & 1;
    float qrow[DK];
    #pragma unroll
    for (int j4 = 0; j4 < 8; ++j4)
        *(float4*)&qrow[j4 * 4] = *(const float4*)&qh[tq * DK + j4 * 4];

    float m_run = NEGV, l_run = 0.f;
    float xacc[DK];
    #pragma unroll
    for (int j = 0; j < DK; ++j) xacc[j] = 0.f;

    const int* __restrict__ amrow = amask + tq * TT;
    for (int i = 0; i < 64; ++i) {
        int tk = half * 64 + i;
        float s = 0.f;
        #pragma unroll
        for (int j4 = 0; j4 < 8; ++j4) {
            float4 k4 = *(const float4*)&kh[tk * DK + j4 * 4];
            s += qrow[j4 * 4 + 0] * k4.x + qrow[j4 * 4 + 1] * k4.y
               + qrow[j4 * 4 + 2] * k4.z + qrow[j4 * 4 + 3] * k4.w;
        }
        s *= SCALEF;
        if (scr[tk] != 0.f || amrow[tk] == 0) s = NEGV;
        if (s > m_run) {             // rare rescale
            float corr = __expf(m_run - s);
            l_run *= corr;
            #pragma unroll
            for (int j = 0; j < DK; ++j) xacc[j] *= corr;
            m_run = s;
        }
        float p = __expf(s - m_run);
        l_run += p;
        #pragma unroll
        for (int j4 = 0; j4 < 8; ++j4) {
            float4 v4 = *(const float4*)&vh[tk * DK + j4 * 4];
            xacc[j4 * 4 + 0] += p * v4.x;
            xacc[j4 * 4 + 1] += p * v4.y;
            xacc[j4 * 4 + 2] += p * v4.z;
            xacc[j4 * 4 + 3] += p * v4.w;
        }
    }

    // ---- merge the two half-row partial softmax states --------------------
    __syncthreads();                 // everyone done reading kh/vh
    scr[256 + tid] = m_run;
    scr[512 + tid] = l_run;
    __syncthreads();
    float mo = scr[256 + (tid ^ 1)];
    float lo = scr[512 + (tid ^ 1)];
    float M = fmaxf(m_run, mo);
    float lsum = l_run * __expf(m_run - M) + lo * __expf(mo - M);
    float sc = __expf(m_run - M) / lsum;

    float* xm = kh;                  // reuse kh's 16 KB for merged x
    if (half == 0) {
        #pragma unroll
        for (int j = 0; j < DK; ++j) xm[tq * DK + j] = xacc[j] * sc;
    }
    __syncthreads();
    if (half == 1) {
        #pragma unroll
        for (int j = 0; j < DK; ++j) xm[tq * DK + j] += xacc[j] * sc;
    }
    __syncthreads();

    // coalesced write of the head slice into x (stored in d_out)
    float* obase = xout + (size_t)bn * TT * DD + h * DK;
    #pragma unroll
    for (int v = 0; v < 4; ++v) {
        int idx = tid * 16 + v * 4;          // 0..4095
        int t = idx >> 5, j = idx & 31;
        *(float4*)&obase[t * DD + j] = *(const float4*)&xm[idx];
    }
}

// ---------------------------------------------------------------------------
// Kernel 2: output projection, in-place on d_out. Each block owns 16 rows:
// loads them to LDS, computes out = x @ out_w^T + out_b, writes back.
// ---------------------------------------------------------------------------
__global__ __launch_bounds__(256, 2) void out_proj_kernel(
    float* __restrict__ io, const float* __restrict__ ow,
    const float* __restrict__ ob)
{
    __shared__ float Xs[16 * 256];    // 16 KB
    __shared__ float Ws[16 * 260];    // ~16.6 KB, [dd][e] with pad 260

    const int tid = threadIdx.x;
    const int tx = tid & 63;          // e = tx*4 + {0..3}
    const int ty = tid >> 6;          // t = ty*4 + {0..3}
    float* iobase = io + (size_t)blockIdx.x * 16 * DD;

    for (int i = tid; i < 1024; i += 256)
        *(float4*)&Xs[i * 4] = *(const float4*)&iobase[i * 4];
    __syncthreads();

    float acc[4][4];
    #pragma unroll
    for (int t = 0; t < 4; ++t)
        #pragma unroll
        for (int e = 0; e < 4; ++e) acc[t][e] = 0.f;

    for (int dc = 0; dc < 16; ++dc) {
        for (int i = tid; i < 4096; i += 256) {
            int e = i >> 4, dd = i & 15;
            Ws[dd * 260 + e] = ow[e * DD + dc * 16 + dd];
        }
        __syncthreads();
        #pragma unroll
        for (int dd = 0; dd < 16; ++dd) {
            float4 w4 = *(const float4*)&Ws[dd * 260 + tx * 4];
            #pragma unroll
            for (int t = 0; t < 4; ++t) {
                float xv = Xs[(ty * 4 + t) * DD + dc * 16 + dd];
                acc[t][0] += xv * w4.x;
                acc[t][1] += xv * w4.y;
                acc[t][2] += xv * w4.z;
                acc[t][3] += xv * w4.w;
            }
        }
        __syncthreads();
    }

    float4 bb = *(const float4*)&ob[tx * 4];
    #pragma unroll
    for (int t = 0; t < 4; ++t) {
        float4 o;
        o.x = acc[t][0] + bb.x;
        o.y = acc[t][1] + bb.y;
        o.z = acc[t][2] + bb.z;
        o.w = acc[t][3] + bb.w;
        *(float4*)&iobase[(ty * 4 + t) * DD + tx * 4] = o;
    }
}

extern "C" void kernel_launch(void* const* d_in, const int* in_sizes, int n_in,
                              void* d_out, int out_size, void* d_ws, size_t ws_size,
                              hipStream_t stream) {
    (void)in_sizes; (void)n_in; (void)d_ws; (void)ws_size; (void)out_size;
    const float* query = (const float*)d_in[0];
    const float* key   = (const float*)d_in[1];
    const float* value = (const float*)d_in[2];
    const void*  kpm   = d_in[3];
    const int*   amask = (const int*)d_in[4];
    const float* wq = (const float*)d_in[5];
    const float* bq = (const float*)d_in[6];
    const float* wk = (const float*)d_in[7];
    const float* bk = (const float*)d_in[8];
    const float* vw = (const float*)d_in[9];
    const float* vb = (const float*)d_in[10];
    const float* ow = (const float*)d_in[11];
    const float* ob = (const float*)d_in[12];
    float* out = (float*)d_out;

    const int BNH = 8 * 64 * HH;              // 4096 blocks
    fused_attn_kernel<<<dim3(BNH), dim3(256), 0, stream>>>(
        query, key, value, (const unsigned char*)kpm, (const int*)kpm, amask,
        wq, bq, wk, bk, vw, vb, out);

    const int NROWBLK = (8 * 64 * TT) / 16;   // 4096 blocks
    out_proj_kernel<<<dim3(NROWBLK), dim3(256), 0, stream>>>(out, ow, ob);
}

// Round 2
// 569.029 us; speedup vs baseline: 4.0166x; 4.0166x over previous
//
#include <hip/hip_runtime.h>

#define TT 128
#define DD 256
#define NH 8
#define HD 32
#define SCALEF 0.17677669529663687f
#define NEGV -1e9f

typedef short bf16x8 __attribute__((ext_vector_type(8)));
typedef float f32x4 __attribute__((ext_vector_type(4)));

__device__ inline unsigned short f2bf(float f) {
    unsigned u = __float_as_uint(f);
    unsigned r = (u + 0x7FFFu + ((u >> 16) & 1u)) >> 16;
    return (unsigned short)r;
}
__device__ inline unsigned pk2(float a, float b) {
    return (unsigned)f2bf(a) | ((unsigned)f2bf(b) << 16);
}

// ---------------------------------------------------------------------------
// Pre-kernel: convert weights to bf16 in workspace.
//   wq,wk: [j][ci][k] fp32 -> [k][j][ci] bf16   (k-major, ci contiguous)
//   vw,ow: [e][d] fp32 -> [e][d] bf16
// ---------------------------------------------------------------------------
__global__ void cvt_weights_kernel(
    const float* __restrict__ wq, const float* __restrict__ wk,
    const float* __restrict__ vw, const float* __restrict__ ow,
    unsigned short* __restrict__ wqb, unsigned short* __restrict__ wkb,
    unsigned short* __restrict__ vwb, unsigned short* __restrict__ owb)
{
    int t = blockIdx.x * 256 + threadIdx.x;          // 0..327679
    if (t < 196608) {
        int k = t >> 16, j = (t >> 8) & 255, ci = t & 255;
        int src = j * 768 + ci * 3 + k;
        wqb[t] = f2bf(wq[src]);
        wkb[t] = f2bf(wk[src]);
    } else {
        int o = t - 196608;
        if (o < 65536) vwb[o] = f2bf(vw[o]);
        else           owb[o - 65536] = f2bf(ow[o - 65536]);
    }
}

// ---------------------------------------------------------------------------
// Main kernel: one block per (b,n,h). 4 waves; wave w owns output rows
// 32w..32w+31. All GEMMs via mfma_f32_16x16x32_bf16.
// LDS map (shorts):
//   U[0..17407]      union: {Xs[130][72] + Wst[3*32][72]} | mask u8[2048] | Ps[128][136]
//   Qs[128][40] @17408   Ks[128][40] @22528   VsT[32][136] @27648
// ---------------------------------------------------------------------------
__global__ __launch_bounds__(256, 2) void fused_attn_mfma(
    const float* __restrict__ query, const float* __restrict__ key,
    const float* __restrict__ value,
    const unsigned char* __restrict__ kpm8, const int* __restrict__ kpm32,
    const int* __restrict__ amask,
    const unsigned short* __restrict__ wqb, const unsigned short* __restrict__ wkb,
    const unsigned short* __restrict__ vwb,
    const float* __restrict__ bq, const float* __restrict__ bk,
    const float* __restrict__ vb,
    float* __restrict__ xout)
{
    __shared__ __align__(16) short lds[32000];
    __shared__ int kpmflag_s;

    const int tid = threadIdx.x;
    // XCD swizzle: 4096 blocks, 8 XCDs -> 8 heads of one (b,n) share an XCD
    int bid = blockIdx.x;
    int bnh = (bid & 7) * 512 + (bid >> 3);
    const int bn = bnh >> 3, h = bnh & 7;

    const int lane = tid & 63;
    const int wv = tid >> 6;
    const int lr = lane & 15;          // A/B frag row (or C col)
    const int rg = lane >> 4;          // k-group / C row group
    const int lk8 = rg * 8;
    const int m0 = wv * 32;

    short* U   = lds;
    short* Qs  = lds + 17408;
    short* Ks  = lds + 22528;
    short* VsT = lds + 27648;
    short* Xs  = U;                    // [130][72]
    short* Wst = U + 9360;             // [3*32][72]
    unsigned char* maskb = (unsigned char*)U;  // [128][16] bitmask bytes
    short* Ps  = U;                    // [128][136]

    // ---- detect key_padding_mask storage width (uint8 vs int32) ----
    {
        bool loc = false;
        for (int i = tid; i < 4096; i += 256)
            if ((i & 3) && kpm8[i]) loc = true;
        if (tid == 0) kpmflag_s = 0;
        __syncthreads();
        if (loc) kpmflag_s = 1;
        __syncthreads();
    }
    const bool kpm_u8 = (kpmflag_s != 0);

    // ================= conv projections: which=0 -> Q, which=1 -> K ========
    const float* Xg[2] = { query + (size_t)bn * TT * DD, key + (size_t)bn * TT * DD };
    const unsigned short* Wg[2] = { wqb, wkb };
    const float* Bg[2] = { bq, bk };
    short* Dst[2] = { Qs, Ks };

    for (int which = 0; which < 2; ++which) {
        const float* __restrict__ X = Xg[which];
        const unsigned short* __restrict__ W = Wg[which];
        f32x4 acc[2][2];
        #pragma unroll
        for (int nf = 0; nf < 2; ++nf) {
            float b = Bg[which][h * HD + nf * 16 + lr];
            f32x4 bv = { b, b, b, b };
            acc[0][nf] = bv; acc[1][nf] = bv;
        }
        for (int cc = 0; cc < 4; ++cc) {
            __syncthreads();
            // stage Xs[130][72]: rows t=-1..128, cols cc*64..+64 (fp32->bf16)
            for (int i = tid; i < 2080; i += 256) {
                int row = i >> 4, c4 = i & 15;
                int g = row - 1;
                float4 x4 = make_float4(0.f, 0.f, 0.f, 0.f);
                if (g >= 0 && g < TT)
                    x4 = *(const float4*)(X + g * DD + cc * 64 + c4 * 4);
                uint2 p; p.x = pk2(x4.x, x4.y); p.y = pk2(x4.z, x4.w);
                *(uint2*)&Xs[row * 72 + c4 * 4] = p;
            }
            // stage Wst[k][n][ci]: 3*32*64 bf16, coalesced b128 copies
            for (int i = tid; i < 768; i += 256) {
                int k = i >> 8, rem = i & 255;
                int n = rem >> 3, c8 = rem & 7;
                uint4 w = *(const uint4*)(W + ((size_t)(k * 256 + h * HD + n) * 256
                                               + cc * 64 + c8 * 8));
                *(uint4*)&Wst[(k * 32 + n) * 72 + c8 * 8] = w;
            }
            __syncthreads();
            #pragma unroll
            for (int k = 0; k < 3; ++k) {
                #pragma unroll
                for (int kk = 0; kk < 2; ++kk) {
                    bf16x8 a0 = *(const bf16x8*)&Xs[(m0 + lr + k) * 72 + kk * 32 + lk8];
                    bf16x8 a1 = *(const bf16x8*)&Xs[(m0 + 16 + lr + k) * 72 + kk * 32 + lk8];
                    bf16x8 b0 = *(const bf16x8*)&Wst[(k * 32 + lr) * 72 + kk * 32 + lk8];
                    bf16x8 b1 = *(const bf16x8*)&Wst[(k * 32 + 16 + lr) * 72 + kk * 32 + lk8];
                    acc[0][0] = __builtin_amdgcn_mfma_f32_16x16x32_bf16(a0, b0, acc[0][0], 0, 0, 0);
                    acc[0][1] = __builtin_amdgcn_mfma_f32_16x16x32_bf16(a0, b1, acc[0][1], 0, 0, 0);
                    acc[1][0] = __builtin_amdgcn_mfma_f32_16x16x32_bf16(a1, b0, acc[1][0], 0, 0, 0);
                    acc[1][1] = __builtin_amdgcn_mfma_f32_16x16x32_bf16(a1, b1, acc[1][1], 0, 0, 0);
                }
            }
        }
        short* D = Dst[which];
        #pragma unroll
        for (int mf = 0; mf < 2; ++mf)
            #pragma unroll
            for (int nf = 0; nf < 2; ++nf)
                #pragma unroll
                for (int r = 0; r < 4; ++r)
                    D[(m0 + mf * 16 + rg * 4 + r) * 40 + nf * 16 + lr] =
                        (short)f2bf(acc[mf][nf][r]);
    }

    // ================= V projection -> VsT[e][t] (transposed) ==============
    {
        const float* __restrict__ Xv = value + (size_t)bn * TT * DD;
        f32x4 acc[2][2];
        #pragma unroll
        for (int nf = 0; nf < 2; ++nf) {
            float b = vb[h * HD + nf * 16 + lr];
            f32x4 bv = { b, b, b, b };
            acc[0][nf] = bv; acc[1][nf] = bv;
        }
        for (int cc = 0; cc < 4; ++cc) {
            __syncthreads();
            for (int i = tid; i < 2048; i += 256) {
                int row = i >> 4, c4 = i & 15;
                float4 x4 = *(const float4*)(Xv + row * DD + cc * 64 + c4 * 4);
                uint2 p; p.x = pk2(x4.x, x4.y); p.y = pk2(x4.z, x4.w);
                *(uint2*)&Xs[row * 72 + c4 * 4] = p;
            }
            for (int i = tid; i < 256; i += 256) {
                int n = i >> 3, c8 = i & 7;
                uint4 w = *(const uint4*)(vwb + ((size_t)(h * HD + n) * 256
                                                 + cc * 64 + c8 * 8));
                *(uint4*)&Wst[n * 72 + c8 * 8] = w;
            }
            __syncthreads();
            #pragma unroll
            for (int kk = 0; kk < 2; ++kk) {
                bf16x8 a0 = *(const bf16x8*)&Xs[(m0 + lr) * 72 + kk * 32 + lk8];
                bf16x8 a1 = *(const bf16x8*)&Xs[(m0 + 16 + lr) * 72 + kk * 32 + lk8];
                bf16x8 b0 = *(const bf16x8*)&Wst[lr * 72 + kk * 32 + lk8];
                bf16x8 b1 = *(const bf16x8*)&Wst[(16 + lr) * 72 + kk * 32 + lk8];
                acc[0][0] = __builtin_amdgcn_mfma_f32_16x16x32_bf16(a0, b0, acc[0][0], 0, 0, 0);
                acc[0][1] = __builtin_amdgcn_mfma_f32_16x16x32_bf16(a0, b1, acc[0][1], 0, 0, 0);
                acc[1][0] = __builtin_amdgcn_mfma_f32_16x16x32_bf16(a1, b0, acc[1][0], 0, 0, 0);
                acc[1][1] = __builtin_amdgcn_mfma_f32_16x16x32_bf16(a1, b1, acc[1][1], 0, 0, 0);
            }
        }
        #pragma unroll
        for (int mf = 0; mf < 2; ++mf)
            #pragma unroll
            for (int nf = 0; nf < 2; ++nf)
                #pragma unroll
                for (int r = 0; r < 4; ++r)
                    VsT[(nf * 16 + lr) * 136 + m0 + mf * 16 + rg * 4 + r] =
                        (short)f2bf(acc[mf][nf][r]);
    }

    // ================= combined mask bitmask (2 KB, in staging region) =====
    __syncthreads();   // all conv/V LDS reads done; QKV tiles complete
    {
        const unsigned char* kp8 = kpm8 + (size_t)bn * TT;
        const int* kp32 = kpm32 + (size_t)bn * TT;
        for (int i = tid; i < 2048; i += 256) {
            int row = i >> 4, c = i & 15;
            unsigned m = 0;
            #pragma unroll
            for (int nf = 0; nf < 8; ++nf) {
                int col = c + nf * 16;
                int kdead = kpm_u8 ? (int)kp8[col] : kp32[col];
                int adead = (amask[row * TT + col] == 0) ? 1 : 0;
                m |= (unsigned)(((kdead != 0) ? 1 : 0) | adead) << nf;
            }
            maskb[i] = (unsigned char)m;
        }
    }
    __syncthreads();

    // ================= QK^T (scores in registers) ==========================
    f32x4 sc[2][8];
    {
        bf16x8 qa[2];
        #pragma unroll
        for (int mf = 0; mf < 2; ++mf)
            qa[mf] = *(const bf16x8*)&Qs[(m0 + mf * 16 + lr) * 40 + lk8];
        #pragma unroll
        for (int nf = 0; nf < 8; ++nf) {
            bf16x8 kb = *(const bf16x8*)&Ks[(nf * 16 + lr) * 40 + lk8];
            f32x4 z = { 0.f, 0.f, 0.f, 0.f };
            sc[0][nf] = __builtin_amdgcn_mfma_f32_16x16x32_bf16(qa[0], kb, z, 0, 0, 0);
            sc[1][nf] = __builtin_amdgcn_mfma_f32_16x16x32_bf16(qa[1], kb, z, 0, 0, 0);
        }
    }

    // ================= mask + softmax (wave-local, 16-lane shuffles) =======
    float linv[2][4];
    #pragma unroll
    for (int mf = 0; mf < 2; ++mf) {
        #pragma unroll
        for (int r = 0; r < 4; ++r) {
            int row = m0 + mf * 16 + rg * 4 + r;
            unsigned mb = maskb[row * 16 + lr];
            float v[8];
            float vmax = -3.4e38f;
            #pragma unroll
            for (int nf = 0; nf < 8; ++nf) {
                float t = sc[mf][nf][r] * SCALEF;
                if ((mb >> nf) & 1) t = NEGV;
                v[nf] = t;
                vmax = fmaxf(vmax, t);
            }
            #pragma unroll
            for (int d = 1; d < 16; d <<= 1)
                vmax = fmaxf(vmax, __shfl_xor(vmax, d, 64));
            float ls = 0.f;
            #pragma unroll
            for (int nf = 0; nf < 8; ++nf) {
                float p = __expf(v[nf] - vmax);
                ls += p;
                sc[mf][nf][r] = p;
            }
            #pragma unroll
            for (int d = 1; d < 16; d <<= 1)
                ls += __shfl_xor(ls, d, 64);
            linv[mf][r] = 1.f / ls;
        }
    }

    __syncthreads();   // all mask-byte reads done; U region becomes Ps

    // write unnormalized P (bf16) — wave-private rows
    #pragma unroll
    for (int mf = 0; mf < 2; ++mf)
        #pragma unroll
        for (int r = 0; r < 4; ++r) {
            int row = m0 + mf * 16 + rg * 4 + r;
            #pragma unroll
            for (int nf = 0; nf < 8; ++nf)
                Ps[row * 136 + nf * 16 + lr] = (short)f2bf(sc[mf][nf][r]);
        }

    // ================= PV ===================================================
    f32x4 xacc[2][2];
    {
        f32x4 z = { 0.f, 0.f, 0.f, 0.f };
        xacc[0][0] = z; xacc[0][1] = z; xacc[1][0] = z; xacc[1][1] = z;
    }
    #pragma unroll
    for (int kk = 0; kk < 4; ++kk) {
        bf16x8 pa0 = *(const bf16x8*)&Ps[(m0 + lr) * 136 + kk * 32 + lk8];
        bf16x8 pa1 = *(const bf16x8*)&Ps[(m0 + 16 + lr) * 136 + kk * 32 + lk8];
        bf16x8 vb0 = *(const bf16x8*)&VsT[lr * 136 + kk * 32 + lk8];
        bf16x8 vb1 = *(const bf16x8*)&VsT[(16 + lr) * 136 + kk * 32 + lk8];
        xacc[0][0] = __builtin_amdgcn_mfma_f32_16x16x32_bf16(pa0, vb0, xacc[0][0], 0, 0, 0);
        xacc[0][1] = __builtin_amdgcn_mfma_f32_16x16x32_bf16(pa0, vb1, xacc[0][1], 0, 0, 0);
        xacc[1][0] = __builtin_amdgcn_mfma_f32_16x16x32_bf16(pa1, vb0, xacc[1][0], 0, 0, 0);
        xacc[1][1] = __builtin_amdgcn_mfma_f32_16x16x32_bf16(pa1, vb1, xacc[1][1], 0, 0, 0);
    }

    // normalize + write x head-slice into d_out (scratch for out-proj)
    float* xo = xout + (size_t)bn * TT * DD + h * HD;
    #pragma unroll
    for (int mf = 0; mf < 2; ++mf)
        #pragma unroll
        for (int nf = 0; nf < 2; ++nf)
            #pragma unroll
            for (int r = 0; r < 4; ++r)
                xo[(m0 + mf * 16 + rg * 4 + r) * DD + nf * 16 + lr] =
                    xacc[mf][nf][r] * linv[mf][r];
}

// ---------------------------------------------------------------------------
// Out-projection (MFMA), in-place on d_out. Block = 128 rows; 4 waves,
// each 32 rows x 256 cols. K=256 in 8 chunks of 32.
// ---------------------------------------------------------------------------
__global__ __launch_bounds__(256, 2) void out_proj_mfma(
    float* __restrict__ xio, const unsigned short* __restrict__ owb,
    const float* __restrict__ ob)
{
    __shared__ __align__(16) short lds2[5120 + 10240];   // Xs[128][40], Ws[256][40]
    short* Xs = lds2;
    short* Ws = lds2 + 5120;

    const int tid = threadIdx.x;
    const int lane = tid & 63, wv = tid >> 6;
    const int lr = lane & 15, rg = lane >> 4, lk8 = rg * 8;
    const int m0 = wv * 32;
    float* base = xio + (size_t)blockIdx.x * TT * DD;

    f32x4 acc[2][16];
    {
        f32x4 z = { 0.f, 0.f, 0.f, 0.f };
        #pragma unroll
        for (int nf = 0; nf < 16; ++nf) { acc[0][nf] = z; acc[1][nf] = z; }
    }

    for (int cc = 0; cc < 8; ++cc) {
        __syncthreads();
        for (int i = tid; i < 1024; i += 256) {
            int row = i >> 3, c4 = i & 7;
            float4 x4 = *(const float4*)(base + row * DD + cc * 32 + c4 * 4);
            uint2 p; p.x = pk2(x4.x, x4.y); p.y = pk2(x4.z, x4.w);
            *(uint2*)&Xs[row * 40 + c4 * 4] = p;
        }
        for (int i = tid; i < 1024; i += 256) {
            int e = i >> 2, c8 = i & 3;
            uint4 w = *(const uint4*)(owb + (size_t)e * 256 + cc * 32 + c8 * 8);
            *(uint4*)&Ws[e * 40 + c8 * 8] = w;
        }
        __syncthreads();
        bf16x8 a0 = *(const bf16x8*)&Xs[(m0 + lr) * 40 + lk8];
        bf16x8 a1 = *(const bf16x8*)&Xs[(m0 + 16 + lr) * 40 + lk8];
        #pragma unroll
        for (int nf = 0; nf < 16; ++nf) {
            bf16x8 b = *(const bf16x8*)&Ws[(nf * 16 + lr) * 40 + lk8];
            acc[0][nf] = __builtin_amdgcn_mfma_f32_16x16x32_bf16(a0, b, acc[0][nf], 0, 0, 0);
            acc[1][nf] = __builtin_amdgcn_mfma_f32_16x16x32_bf16(a1, b, acc[1][nf], 0, 0, 0);
        }
    }

    #pragma unroll
    for (int mf = 0; mf < 2; ++mf)
        #pragma unroll
        for (int nf = 0; nf < 16; ++nf) {
            float bb = ob[nf * 16 + lr];
            #pragma unroll
            for (int r = 0; r < 4; ++r)
                base[(m0 + mf * 16 + rg * 4 + r) * DD + nf * 16 + lr] =
                    acc[mf][nf][r] + bb;
        }
}

extern "C" void kernel_launch(void* const* d_in, const int* in_sizes, int n_in,
                              void* d_out, int out_size, void* d_ws, size_t ws_size,
                              hipStream_t stream) {
    (void)in_sizes; (void)n_in; (void)out_size; (void)ws_size;
    const float* query = (const float*)d_in[0];
    const float* key   = (const float*)d_in[1];
    const float* value = (const float*)d_in[2];
    const void*  kpm   = d_in[3];
    const int*   amask = (const int*)d_in[4];
    const float* wq = (const float*)d_in[5];
    const float* bq = (const float*)d_in[6];
    const float* wk = (const float*)d_in[7];
    const float* bk = (const float*)d_in[8];
    const float* vw = (const float*)d_in[9];
    const float* vb = (const float*)d_in[10];
    const float* ow = (const float*)d_in[11];
    const float* ob = (const float*)d_in[12];
    float* out = (float*)d_out;

    unsigned short* wqb = (unsigned short*)d_ws;
    unsigned short* wkb = wqb + 196608;
    unsigned short* vwb = wkb + 196608;
    unsigned short* owb = vwb + 65536;   // total 524288 shorts = 1 MiB

    cvt_weights_kernel<<<dim3(1280), dim3(256), 0, stream>>>(
        wq, wk, vw, ow, wqb, wkb, vwb, owb);

    fused_attn_mfma<<<dim3(4096), dim3(256), 0, stream>>>(
        query, key, value, (const unsigned char*)kpm, (const int*)kpm, amask,
        wqb, wkb, vwb, bq, bk, vb, out);

    out_proj_mfma<<<dim3(512), dim3(256), 0, stream>>>(out, owb, ob);
}

// Round 3
// 283.157 us; speedup vs baseline: 8.0718x; 2.0096x over previous
//
#include <hip/hip_runtime.h>

#define TT 128
#define DD 256
#define NH 8
#define HD 32
#define SCALEF 0.17677669529663687f
#define NEGV -1e9f

typedef short bf16x8 __attribute__((ext_vector_type(8)));
typedef float f32x4 __attribute__((ext_vector_type(4)));

__device__ inline unsigned short f2bf(float f) {
    unsigned u = __float_as_uint(f);
    unsigned r = (u + 0x7FFFu + ((u >> 16) & 1u)) >> 16;
    return (unsigned short)r;
}
__device__ inline unsigned pk2(float a, float b) {
    return (unsigned)f2bf(a) | ((unsigned)f2bf(b) << 16);
}

// ---------------------------------------------------------------------------
// Kernel 0: weights -> bf16 in ws; block 1280 detects kpm storage width.
//   wq,wk: [j][ci][k] fp32 -> [k][j][ci] bf16
//   vw,ow: [e][d] fp32 -> [e][d] bf16
// ---------------------------------------------------------------------------
__global__ void cvt_weights_kernel(
    const float* __restrict__ wq, const float* __restrict__ wk,
    const float* __restrict__ vw, const float* __restrict__ ow,
    const unsigned char* __restrict__ kpm8,
    unsigned short* __restrict__ wqb, unsigned short* __restrict__ wkb,
    unsigned short* __restrict__ vwb, unsigned short* __restrict__ owb,
    int* __restrict__ flagp)
{
    if (blockIdx.x == 1280) {
        __shared__ int f;
        if (threadIdx.x == 0) f = 0;
        __syncthreads();
        bool loc = false;
        for (int i = threadIdx.x; i < 4096; i += 256)
            if ((i & 3) && kpm8[i]) loc = true;
        if (loc) f = 1;
        __syncthreads();
        if (threadIdx.x == 0) *flagp = f;
        return;
    }
    int t = blockIdx.x * 256 + threadIdx.x;          // 0..327679
    if (t < 196608) {
        int k = t >> 16, j = (t >> 8) & 255, ci = t & 255;
        int src = j * 768 + ci * 3 + k;
        wqb[t] = f2bf(wq[src]);
        wkb[t] = f2bf(wk[src]);
    } else {
        int o = t - 196608;
        if (o < 65536) vwb[o] = f2bf(vw[o]);
        else           owb[o - 65536] = f2bf(ow[o - 65536]);
    }
}

// ---------------------------------------------------------------------------
// Kernel 1: projections. grid (512 bn, 3 which). 4 waves.
//  which 0/1: conv Q/K.  A = W rows j (global L2), B = X rows t (LDS, k-shift).
//             C[j][t] -> store bf16 [t][j] into d_out cell (8B packed stores).
//  which 2:   V-proj.    A = X rows t (LDS), B = vw rows e (global L2).
//             C[t][e] -> store bf16 V^T [e][t] into ws (8B packed stores).
// ---------------------------------------------------------------------------
__global__ __launch_bounds__(256, 2) void proj_kernel(
    const float* __restrict__ query, const float* __restrict__ key,
    const float* __restrict__ value,
    const unsigned short* __restrict__ wqb, const unsigned short* __restrict__ wkb,
    const unsigned short* __restrict__ vwb,
    const float* __restrict__ bq, const float* __restrict__ bk,
    const float* __restrict__ vbias,
    short* __restrict__ qkb, short* __restrict__ vbuf)
{
    __shared__ __align__(16) short Xs[130 * 72];   // 18.7 KB

    const int tid = threadIdx.x;
    const int bn = blockIdx.x, which = blockIdx.y;
    const int lane = tid & 63, wv = tid >> 6;
    const int lr = lane & 15, rg = lane >> 4, k8 = rg * 8;

    const float* __restrict__ X =
        (which == 0 ? query : which == 1 ? key : value) + (size_t)bn * TT * DD;

    if (which < 2) {
        const unsigned short* __restrict__ W = which ? wkb : wqb;
        const float* __restrict__ bias = which ? bk : bq;
        const int j0 = wv * 64;

        f32x4 acc[4][8];
        #pragma unroll
        for (int mf = 0; mf < 4; ++mf)
            #pragma unroll
            for (int r = 0; r < 4; ++r) {
                float bv = bias[j0 + mf * 16 + rg * 4 + r];
                #pragma unroll
                for (int nf = 0; nf < 8; ++nf) acc[mf][nf][r] = bv;
            }

        for (int cc = 0; cc < 4; ++cc) {
            __syncthreads();
            for (int i = tid; i < 2080; i += 256) {     // rows -1..128
                int row = i >> 4, c4 = i & 15;
                int g = row - 1;
                float4 x4 = make_float4(0.f, 0.f, 0.f, 0.f);
                if (g >= 0 && g < TT)
                    x4 = *(const float4*)(X + g * DD + cc * 64 + c4 * 4);
                uint2 p; p.x = pk2(x4.x, x4.y); p.y = pk2(x4.z, x4.w);
                *(uint2*)&Xs[row * 72 + c4 * 4] = p;
            }
            __syncthreads();
            #pragma unroll
            for (int k = 0; k < 3; ++k) {
                #pragma unroll
                for (int kk = 0; kk < 2; ++kk) {
                    bf16x8 aa[4];
                    #pragma unroll
                    for (int mf = 0; mf < 4; ++mf)
                        aa[mf] = *(const bf16x8*)(W +
                            ((size_t)(k * 256 + j0 + mf * 16 + lr) * 256
                             + cc * 64 + kk * 32 + k8));
                    #pragma unroll
                    for (int nf = 0; nf < 8; ++nf) {
                        bf16x8 bb = *(const bf16x8*)&Xs[(nf * 16 + lr + k) * 72
                                                        + kk * 32 + k8];
                        #pragma unroll
                        for (int mf = 0; mf < 4; ++mf)
                            acc[mf][nf] = __builtin_amdgcn_mfma_f32_16x16x32_bf16(
                                aa[mf], bb, acc[mf][nf], 0, 0, 0);
                    }
                }
            }
        }
        // store: [t][j] bf16, 8B per (mf,nf)
        short* cell = qkb + (size_t)bn * 65536 + which * 32768;
        #pragma unroll
        for (int mf = 0; mf < 4; ++mf)
            #pragma unroll
            for (int nf = 0; nf < 8; ++nf) {
                int t = nf * 16 + lr, j = j0 + mf * 16 + rg * 4;
                uint2 p;
                p.x = pk2(acc[mf][nf][0], acc[mf][nf][1]);
                p.y = pk2(acc[mf][nf][2], acc[mf][nf][3]);
                *(uint2*)&cell[t * 256 + j] = p;
            }
    } else {
        const int t0 = wv * 32;
        f32x4 acc[2][16];
        #pragma unroll
        for (int nf = 0; nf < 16; ++nf) {
            float bv = vbias[nf * 16 + lr];
            #pragma unroll
            for (int mf = 0; mf < 2; ++mf)
                #pragma unroll
                for (int r = 0; r < 4; ++r) acc[mf][nf][r] = bv;
        }
        for (int cc = 0; cc < 4; ++cc) {
            __syncthreads();
            for (int i = tid; i < 2048; i += 256) {
                int row = i >> 4, c4 = i & 15;
                float4 x4 = *(const float4*)(X + row * DD + cc * 64 + c4 * 4);
                uint2 p; p.x = pk2(x4.x, x4.y); p.y = pk2(x4.z, x4.w);
                *(uint2*)&Xs[row * 72 + c4 * 4] = p;
            }
            __syncthreads();
            #pragma unroll
            for (int kk = 0; kk < 2; ++kk) {
                bf16x8 aa[2];
                #pragma unroll
                for (int mf = 0; mf < 2; ++mf)
                    aa[mf] = *(const bf16x8*)&Xs[(t0 + mf * 16 + lr) * 72
                                                 + kk * 32 + k8];
                #pragma unroll
                for (int nf = 0; nf < 16; ++nf) {
                    bf16x8 bb = *(const bf16x8*)(vwb +
                        ((size_t)(nf * 16 + lr) * 256 + cc * 64 + kk * 32 + k8));
                    #pragma unroll
                    for (int mf = 0; mf < 2; ++mf)
                        acc[mf][nf] = __builtin_amdgcn_mfma_f32_16x16x32_bf16(
                            aa[mf], bb, acc[mf][nf], 0, 0, 0);
                }
            }
        }
        // store V^T: [e][t], 8B per (mf,nf)
        short* vcell = vbuf + (size_t)bn * 32768;
        #pragma unroll
        for (int mf = 0; mf < 2; ++mf)
            #pragma unroll
            for (int nf = 0; nf < 16; ++nf) {
                int e = nf * 16 + lr, t = t0 + mf * 16 + rg * 4;
                uint2 p;
                p.x = pk2(acc[mf][nf][0], acc[mf][nf][1]);
                p.y = pk2(acc[mf][nf][2], acc[mf][nf][3]);
                *(uint2*)&vcell[e * 128 + t] = p;
            }
    }
}

// ---------------------------------------------------------------------------
// Kernel 2: attention. grid 4096 = (bn,h) XCD-swizzled, 4 waves.
// Q/K frags loaded bf16 global->reg; P via per-wave LDS; x bf16 written over
// this block's own K head-slice (64B-aligned lines, race-free).
// ---------------------------------------------------------------------------
__global__ __launch_bounds__(256, 2) void attn_kernel(
    short* __restrict__ qkb, const short* __restrict__ vbuf,
    const unsigned char* __restrict__ kpm8, const int* __restrict__ kpm32,
    const int* __restrict__ amask, const int* __restrict__ flagp)
{
    __shared__ __align__(16) short Ps[4 * 32 * 136];   // 34.8 KB, per-wave
    __shared__ unsigned char maskb[2048];

    const int tid = threadIdx.x;
    int bid = blockIdx.x;
    int bnh = (bid & 7) * 512 + (bid >> 3);
    const int bn = bnh >> 3, h = bnh & 7;

    const int lane = tid & 63, wv = tid >> 6;
    const int lr = lane & 15, rg = lane >> 4, k8 = rg * 8;
    const int m0 = wv * 32;
    const bool kpm_u8 = (*flagp != 0);

    // build combined mask bitmask
    {
        const unsigned char* kp8 = kpm8 + (size_t)bn * TT;
        const int* kp32 = kpm32 + (size_t)bn * TT;
        for (int i = tid; i < 2048; i += 256) {
            int row = i >> 4, c = i & 15;
            unsigned m = 0;
            #pragma unroll
            for (int nf = 0; nf < 8; ++nf) {
                int col = c + nf * 16;
                int kdead = kpm_u8 ? (int)kp8[col] : kp32[col];
                int adead = (amask[row * TT + col] == 0) ? 1 : 0;
                m |= (unsigned)(((kdead != 0) ? 1 : 0) | adead) << nf;
            }
            maskb[i] = (unsigned char)m;
        }
    }

    const short* qcell = qkb + (size_t)bn * 65536;
    short* kcell = qkb + (size_t)bn * 65536 + 32768;

    bf16x8 qa[2];
    #pragma unroll
    for (int mf = 0; mf < 2; ++mf)
        qa[mf] = *(const bf16x8*)&qcell[(m0 + mf * 16 + lr) * 256 + h * HD + k8];
    bf16x8 kb[8];
    #pragma unroll
    for (int nf = 0; nf < 8; ++nf)
        kb[nf] = *(const bf16x8*)&kcell[(nf * 16 + lr) * 256 + h * HD + k8];

    __syncthreads();   // maskb ready

    // QK^T
    f32x4 sc[2][8];
    #pragma unroll
    for (int nf = 0; nf < 8; ++nf) {
        f32x4 z = { 0.f, 0.f, 0.f, 0.f };
        sc[0][nf] = __builtin_amdgcn_mfma_f32_16x16x32_bf16(qa[0], kb[nf], z, 0, 0, 0);
        sc[1][nf] = __builtin_amdgcn_mfma_f32_16x16x32_bf16(qa[1], kb[nf], z, 0, 0, 0);
    }

    // mask + softmax (16-lane groups own a row)
    float linv[2][4];
    #pragma unroll
    for (int mf = 0; mf < 2; ++mf)
        #pragma unroll
        for (int r = 0; r < 4; ++r) {
            int row = m0 + mf * 16 + rg * 4 + r;
            unsigned mb = maskb[row * 16 + lr];
            float v[8];
            float vmax = -3.4e38f;
            #pragma unroll
            for (int nf = 0; nf < 8; ++nf) {
                float t = sc[mf][nf][r] * SCALEF;
                if ((mb >> nf) & 1) t = NEGV;
                v[nf] = t;
                vmax = fmaxf(vmax, t);
            }
            #pragma unroll
            for (int d = 1; d < 16; d <<= 1)
                vmax = fmaxf(vmax, __shfl_xor(vmax, d, 64));
            float ls = 0.f;
            #pragma unroll
            for (int nf = 0; nf < 8; ++nf) {
                float p = __expf(v[nf] - vmax);
                ls += p;
                sc[mf][nf][r] = p;
            }
            #pragma unroll
            for (int d = 1; d < 16; d <<= 1)
                ls += __shfl_xor(ls, d, 64);
            linv[mf][r] = 1.f / ls;
        }

    // P -> per-wave LDS
    short* Pw = Ps + wv * 32 * 136;
    #pragma unroll
    for (int mf = 0; mf < 2; ++mf)
        #pragma unroll
        for (int r = 0; r < 4; ++r) {
            int q = mf * 16 + rg * 4 + r;
            #pragma unroll
            for (int nf = 0; nf < 8; ++nf)
                Pw[q * 136 + nf * 16 + lr] = (short)f2bf(sc[mf][nf][r]);
        }

    // PV: A = P (LDS), B = V^T rows e (global)
    f32x4 xacc[2][2];
    {
        f32x4 z = { 0.f, 0.f, 0.f, 0.f };
        xacc[0][0] = z; xacc[0][1] = z; xacc[1][0] = z; xacc[1][1] = z;
    }
    const short* vcell = vbuf + (size_t)bn * 32768;
    #pragma unroll
    for (int kk = 0; kk < 4; ++kk) {
        bf16x8 pa0 = *(const bf16x8*)&Pw[(lr) * 136 + kk * 32 + k8];
        bf16x8 pa1 = *(const bf16x8*)&Pw[(16 + lr) * 136 + kk * 32 + k8];
        bf16x8 vb0 = *(const bf16x8*)&vcell[(h * HD + lr) * 128 + kk * 32 + k8];
        bf16x8 vb1 = *(const bf16x8*)&vcell[(h * HD + 16 + lr) * 128 + kk * 32 + k8];
        xacc[0][0] = __builtin_amdgcn_mfma_f32_16x16x32_bf16(pa0, vb0, xacc[0][0], 0, 0, 0);
        xacc[0][1] = __builtin_amdgcn_mfma_f32_16x16x32_bf16(pa0, vb1, xacc[0][1], 0, 0, 0);
        xacc[1][0] = __builtin_amdgcn_mfma_f32_16x16x32_bf16(pa1, vb0, xacc[1][0], 0, 0, 0);
        xacc[1][1] = __builtin_amdgcn_mfma_f32_16x16x32_bf16(pa1, vb1, xacc[1][1], 0, 0, 0);
    }

    __syncthreads();   // all waves' K-frag loads landed before x overwrites K

    // x (bf16) over own K head-slice
    #pragma unroll
    for (int mf = 0; mf < 2; ++mf)
        #pragma unroll
        for (int nf = 0; nf < 2; ++nf)
            #pragma unroll
            for (int r = 0; r < 4; ++r) {
                int t = m0 + mf * 16 + rg * 4 + r;
                kcell[t * 256 + h * HD + nf * 16 + lr] =
                    (short)f2bf(xacc[mf][nf][r] * linv[mf][r]);
            }
}

// ---------------------------------------------------------------------------
// Kernel 3: out-projection, in-place. Reads bf16 x from K-half of cell,
// writes fp32 over the full cell. grid 512 (bn), 4 waves.
// ---------------------------------------------------------------------------
__global__ __launch_bounds__(256, 2) void out_proj_mfma(
    short* __restrict__ qkb, const unsigned short* __restrict__ owb,
    const float* __restrict__ ob)
{
    __shared__ __align__(16) short lds2[5120 + 10240];   // Xs[128][40], Ws[256][40]
    short* Xs = lds2;
    short* Ws = lds2 + 5120;

    const int tid = threadIdx.x;
    const int lane = tid & 63, wv = tid >> 6;
    const int lr = lane & 15, rg = lane >> 4, k8 = rg * 8;
    const int m0 = wv * 32;
    const short* xsrc = qkb + (size_t)blockIdx.x * 65536 + 32768;
    float* fcell = (float*)qkb + (size_t)blockIdx.x * 32768;

    f32x4 acc[2][16];
    {
        f32x4 z = { 0.f, 0.f, 0.f, 0.f };
        #pragma unroll
        for (int nf = 0; nf < 16; ++nf) { acc[0][nf] = z; acc[1][nf] = z; }
    }

    for (int cc = 0; cc < 8; ++cc) {
        __syncthreads();
        for (int i = tid; i < 512; i += 256) {
            int row = i >> 2, c8 = i & 3;
            *(uint4*)&Xs[row * 40 + c8 * 8] =
                *(const uint4*)&xsrc[row * 256 + cc * 32 + c8 * 8];
        }
        for (int i = tid; i < 1024; i += 256) {
            int e = i >> 2, c8 = i & 3;
            *(uint4*)&Ws[e * 40 + c8 * 8] =
                *(const uint4*)(owb + (size_t)e * 256 + cc * 32 + c8 * 8);
        }
        __syncthreads();
        bf16x8 a0 = *(const bf16x8*)&Xs[(m0 + lr) * 40 + k8];
        bf16x8 a1 = *(const bf16x8*)&Xs[(m0 + 16 + lr) * 40 + k8];
        #pragma unroll
        for (int nf = 0; nf < 16; ++nf) {
            bf16x8 b = *(const bf16x8*)&Ws[(nf * 16 + lr) * 40 + k8];
            acc[0][nf] = __builtin_amdgcn_mfma_f32_16x16x32_bf16(a0, b, acc[0][nf], 0, 0, 0);
            acc[1][nf] = __builtin_amdgcn_mfma_f32_16x16x32_bf16(a1, b, acc[1][nf], 0, 0, 0);
        }
    }

    #pragma unroll
    for (int mf = 0; mf < 2; ++mf)
        #pragma unroll
        for (int nf = 0; nf < 16; ++nf) {
            float bb = ob[nf * 16 + lr];
            #pragma unroll
            for (int r = 0; r < 4; ++r)
                fcell[(m0 + mf * 16 + rg * 4 + r) * DD + nf * 16 + lr] =
                    acc[mf][nf][r] + bb;
        }
}

extern "C" void kernel_launch(void* const* d_in, const int* in_sizes, int n_in,
                              void* d_out, int out_size, void* d_ws, size_t ws_size,
                              hipStream_t stream) {
    (void)in_sizes; (void)n_in; (void)out_size; (void)ws_size;
    const float* query = (const float*)d_in[0];
    const float* key   = (const float*)d_in[1];
    const float* value = (const float*)d_in[2];
    const void*  kpm   = d_in[3];
    const int*   amask = (const int*)d_in[4];
    const float* wq = (const float*)d_in[5];
    const float* bq = (const float*)d_in[6];
    const float* wk = (const float*)d_in[7];
    const float* bk = (const float*)d_in[8];
    const float* vw = (const float*)d_in[9];
    const float* vb = (const float*)d_in[10];
    const float* ow = (const float*)d_in[11];
    const float* ob = (const float*)d_in[12];

    short* qkb = (short*)d_out;
    unsigned short* wqb = (unsigned short*)d_ws;        // 196608
    unsigned short* wkb = wqb + 196608;                 // 196608
    unsigned short* vwb = wkb + 196608;                 // 65536
    unsigned short* owb = vwb + 65536;                  // 65536  (end 524288)
    int* flagp = (int*)((short*)d_ws + 524288);
    short* vbuf = (short*)d_ws + 524296;                // 16.77M shorts (32 MiB)

    cvt_weights_kernel<<<dim3(1281), dim3(256), 0, stream>>>(
        wq, wk, vw, ow, (const unsigned char*)kpm, wqb, wkb, vwb, owb, flagp);

    proj_kernel<<<dim3(512, 3), dim3(256), 0, stream>>>(
        query, key, value, wqb, wkb, vwb, bq, bk, vb, qkb, vbuf);

    attn_kernel<<<dim3(4096), dim3(256), 0, stream>>>(
        qkb, vbuf, (const unsigned char*)kpm, (const int*)kpm, amask, flagp);

    out_proj_mfma<<<dim3(512), dim3(256), 0, stream>>>(qkb, owb, ob);
}